// Round 4
// baseline (184.120 us; speedup 1.0000x reference)
//
#include <hip/hip_runtime.h>
#include <hip/hip_bf16.h>
#include <hip/hip_cooperative_groups.h>

namespace cg = cooperative_groups;

#define D 128
#define LPE 16              // lanes per node group (each lane owns 8 dims)
#define BLOCK 256
#define GRID 1024           // 4 blocks/CU on 256 CUs -> co-resident, cooperative-safe

// Fused: phase 1 (pu[n]=dot(h[n],Wu), pv[n]=dot(h[n],Wv)) -> grid sync ->
// phase 2 (out[e]=pu[src[e]]+pv[dst[e]]+b). Phase-2 indices are prefetched
// into registers BEFORE phase 1 so the 5 MB index stream overlaps the
// 51.2 MB h stream.
__global__ __launch_bounds__(BLOCK, 4) void fused_edge_mlp(
    const float* __restrict__ h,
    const int*   __restrict__ src,
    const int*   __restrict__ dst,
    const float* __restrict__ W_w,   // [2*D] : first D = Wu, next D = Wv
    const float* __restrict__ W_b,   // [1]
    float*       __restrict__ pu,    // [n_nodes] scratch
    float*       __restrict__ pv,    // [n_nodes] scratch
    float*       __restrict__ out,   // [n_edges]
    int n_nodes, int n_edges)
{
    const int tid  = blockIdx.x * BLOCK + threadIdx.x;
    const int lane = threadIdx.x & (LPE - 1);

    // ---- Prefetch this thread's phase-2 indices (overlaps h streaming) ----
    const int n_quads = n_edges >> 2;            // 156250 < 262144 threads
    int4 qs = make_int4(0, 0, 0, 0);
    int4 qd = make_int4(0, 0, 0, 0);
    const bool have_quad = tid < n_quads;
    if (have_quad) {
        qs = reinterpret_cast<const int4*>(src)[tid];
        qd = reinterpret_cast<const int4*>(dst)[tid];
    }

    // ---- Per-lane weights ----
    float wu[8], wv[8];
#pragma unroll
    for (int j = 0; j < 8; ++j) {
        wu[j] = W_w[lane * 8 + j];
        wv[j] = W_w[D + lane * 8 + j];
    }
    const float bias = W_b[0];

    // ---- Phase 1: grid-stride over node pairs (2 nodes / 16-lane group) ----
    const int group   = tid >> 4;
    const int ngroups = (GRID * BLOCK) >> 4;     // 16384 groups
    for (int n0 = group * 2; n0 < n_nodes; n0 += ngroups * 2) {
        const bool has1 = (n0 + 1) < n_nodes;
        const float4* hp0 = reinterpret_cast<const float4*>(h + (size_t)n0 * D) + lane * 2;
        const float4* hp1 = reinterpret_cast<const float4*>(h + (size_t)(has1 ? n0 + 1 : n0) * D) + lane * 2;

        float4 a0 = hp0[0];
        float4 a1 = hp0[1];
        float4 b0 = hp1[0];
        float4 b1 = hp1[1];

        float su0 = a0.x * wu[0] + a0.y * wu[1] + a0.z * wu[2] + a0.w * wu[3]
                  + a1.x * wu[4] + a1.y * wu[5] + a1.z * wu[6] + a1.w * wu[7];
        float sv0 = a0.x * wv[0] + a0.y * wv[1] + a0.z * wv[2] + a0.w * wv[3]
                  + a1.x * wv[4] + a1.y * wv[5] + a1.z * wv[6] + a1.w * wv[7];
        float su1 = b0.x * wu[0] + b0.y * wu[1] + b0.z * wu[2] + b0.w * wu[3]
                  + b1.x * wu[4] + b1.y * wu[5] + b1.z * wu[6] + b1.w * wu[7];
        float sv1 = b0.x * wv[0] + b0.y * wv[1] + b0.z * wv[2] + b0.w * wv[3]
                  + b1.x * wv[4] + b1.y * wv[5] + b1.z * wv[6] + b1.w * wv[7];

#pragma unroll
        for (int off = 1; off < LPE; off <<= 1) {
            su0 += __shfl_xor(su0, off, 64);
            sv0 += __shfl_xor(sv0, off, 64);
            su1 += __shfl_xor(su1, off, 64);
            sv1 += __shfl_xor(sv1, off, 64);
        }

        if (lane == 0) {
            pu[n0] = su0;
            pv[n0] = sv0;
            if (has1) {
                pu[n0 + 1] = su1;
                pv[n0 + 1] = sv1;
            }
        }
    }

    // ---- Grid-wide barrier (device-scope visibility of pu/pv) ----
    __threadfence();
    cg::this_grid().sync();

    // ---- Phase 2: 4 edges per thread, indices already in registers ----
    if (have_quad) {
        float4 r;
        r.x = pu[qs.x] + pv[qd.x] + bias;
        r.y = pu[qs.y] + pv[qd.y] + bias;
        r.z = pu[qs.z] + pv[qd.z] + bias;
        r.w = pu[qs.w] + pv[qd.w] + bias;
        reinterpret_cast<float4*>(out)[tid] = r;
    }
    // Defensive tail (no-op for 625000).
    if (tid == 0) {
        for (int e = n_quads << 2; e < n_edges; ++e)
            out[e] = pu[src[e]] + pv[dst[e]] + bias;
    }
}

extern "C" void kernel_launch(void* const* d_in, const int* in_sizes, int n_in,
                              void* d_out, int out_size, void* d_ws, size_t ws_size,
                              hipStream_t stream)
{
    const float* h   = (const float*)d_in[0];
    const int*   src = (const int*)d_in[1];
    const int*   dst = (const int*)d_in[2];
    const float* W_w = (const float*)d_in[3];
    const float* W_b = (const float*)d_in[4];
    float*       out = (float*)d_out;

    int n_nodes = in_sizes[0] / D;   // 100000
    int n_edges = in_sizes[1];       // 625000

    float* pu = (float*)d_ws;
    float* pv = pu + n_nodes;

    void* args[] = {
        (void*)&h, (void*)&src, (void*)&dst, (void*)&W_w, (void*)&W_b,
        (void*)&pu, (void*)&pv, (void*)&out, (void*)&n_nodes, (void*)&n_edges
    };
    hipLaunchCooperativeKernel(reinterpret_cast<const void*>(fused_edge_mlp),
                               dim3(GRID), dim3(BLOCK), args, 0, stream);
}

// Round 5
// 49.891 us; speedup vs baseline: 3.6904x; 3.6904x over previous
//
#include <hip/hip_runtime.h>
#include <hip/hip_bf16.h>

#define D 128
#define LPE 16              // lanes per node-group (each lane owns 8 dims)
#define BLOCK 256
#define NPG 2               // nodes per 16-lane group

// Phase 1: pu[n] = dot(h[n], Wu), pv[n] = dot(h[n], Wv).  (identical to R3)
__global__ __launch_bounds__(BLOCK) void node_proj_kernel(
    const float* __restrict__ h,
    const float* __restrict__ W_w,   // [2*D] : first D = Wu, next D = Wv
    float*       __restrict__ pu,    // [n_nodes]
    float*       __restrict__ pv,    // [n_nodes]
    int n_nodes)
{
    const int lane = threadIdx.x & (LPE - 1);

    float wu[8], wv[8];
#pragma unroll
    for (int j = 0; j < 8; ++j) {
        wu[j] = W_w[lane * 8 + j];
        wv[j] = W_w[D + lane * 8 + j];
    }

    const int group = (blockIdx.x * BLOCK + threadIdx.x) >> 4;
    const int n0 = group * NPG;
    if (n0 >= n_nodes) return;

    const float4* hp0 = reinterpret_cast<const float4*>(h + (size_t)n0 * D) + lane * 2;
    const bool has1 = (n0 + 1) < n_nodes;
    const float4* hp1 = reinterpret_cast<const float4*>(h + (size_t)(has1 ? n0 + 1 : n0) * D) + lane * 2;

    float4 a0 = hp0[0];
    float4 a1 = hp0[1];
    float4 b0 = hp1[0];
    float4 b1 = hp1[1];

    float su0 = a0.x * wu[0] + a0.y * wu[1] + a0.z * wu[2] + a0.w * wu[3]
              + a1.x * wu[4] + a1.y * wu[5] + a1.z * wu[6] + a1.w * wu[7];
    float sv0 = a0.x * wv[0] + a0.y * wv[1] + a0.z * wv[2] + a0.w * wv[3]
              + a1.x * wv[4] + a1.y * wv[5] + a1.z * wv[6] + a1.w * wv[7];
    float su1 = b0.x * wu[0] + b0.y * wu[1] + b0.z * wu[2] + b0.w * wu[3]
              + b1.x * wu[4] + b1.y * wu[5] + b1.z * wu[6] + b1.w * wu[7];
    float sv1 = b0.x * wv[0] + b0.y * wv[1] + b0.z * wv[2] + b0.w * wv[3]
              + b1.x * wv[4] + b1.y * wv[5] + b1.z * wv[6] + b1.w * wv[7];

#pragma unroll
    for (int off = 1; off < LPE; off <<= 1) {
        su0 += __shfl_xor(su0, off, 64);
        sv0 += __shfl_xor(sv0, off, 64);
        su1 += __shfl_xor(su1, off, 64);
        sv1 += __shfl_xor(sv1, off, 64);
    }

    if (lane == 0) {
        pu[n0] = su0;
        pv[n0] = sv0;
        if (has1) {
            pu[n0 + 1] = su1;
            pv[n0 + 1] = sv1;
        }
    }
}

// Phase 2: out[e] = pu[src[e]] + pv[dst[e]] + b.  (identical to R3)
__global__ __launch_bounds__(BLOCK) void edge_score_kernel(
    const float* __restrict__ pu,
    const float* __restrict__ pv,
    const int*   __restrict__ src,
    const int*   __restrict__ dst,
    const float* __restrict__ W_b,
    float*       __restrict__ out,
    int n_edges)
{
    const float bias = W_b[0];
    const int n_quads = n_edges >> 2;
    const int q = blockIdx.x * BLOCK + threadIdx.x;

    if (q < n_quads) {
        int4 s = reinterpret_cast<const int4*>(src)[q];
        int4 d = reinterpret_cast<const int4*>(dst)[q];
        float4 r;
        r.x = pu[s.x] + pv[d.x] + bias;
        r.y = pu[s.y] + pv[d.y] + bias;
        r.z = pu[s.z] + pv[d.z] + bias;
        r.w = pu[s.w] + pv[d.w] + bias;
        reinterpret_cast<float4*>(out)[q] = r;
    }

    if (q == 0) {
        for (int e = n_quads << 2; e < n_edges; ++e)
            out[e] = pu[src[e]] + pv[dst[e]] + bias;
    }
}

extern "C" void kernel_launch(void* const* d_in, const int* in_sizes, int n_in,
                              void* d_out, int out_size, void* d_ws, size_t ws_size,
                              hipStream_t stream)
{
    const float* h   = (const float*)d_in[0];
    const int*   src = (const int*)d_in[1];
    const int*   dst = (const int*)d_in[2];
    const float* W_w = (const float*)d_in[3];
    const float* W_b = (const float*)d_in[4];
    float*       out = (float*)d_out;

    const int n_nodes = in_sizes[0] / D;   // 100000
    const int n_edges = in_sizes[1];       // 625000

    float* pu = (float*)d_ws;
    float* pv = pu + n_nodes;

    const int groups1 = (n_nodes + NPG - 1) / NPG;
    const int blocks1 = (groups1 * LPE + BLOCK - 1) / BLOCK;       // 3125
    node_proj_kernel<<<blocks1, BLOCK, 0, stream>>>(h, W_w, pu, pv, n_nodes);

    // DIAGNOSTIC: launch phase 2 five times (idempotent — identical output).
    // dur = p1 + 5*p2; with R3's p1+p2=21.9 us -> p2 = (dur-21.9)/4.
    const int n_quads = n_edges >> 2;
    const int blocks2 = (n_quads + BLOCK - 1) / BLOCK;             // 611
    for (int rep = 0; rep < 5; ++rep) {
        edge_score_kernel<<<blocks2, BLOCK, 0, stream>>>(pu, pv, src, dst, W_b, out, n_edges);
    }
}

// Round 6
// 25.013 us; speedup vs baseline: 7.3610x; 1.9946x over previous
//
#include <hip/hip_runtime.h>
#include <hip/hip_bf16.h>

#define D 128
#define BLOCK 256
#define ROWS_PER_WAVE 16            // 8 KB of h per wave
#define CHUNKS (ROWS_PER_WAVE / 2)  // 1 KB (2 rows) per chunk

// Phase 1: pu[n]=dot(h[n],Wu), pv[n]=dot(h[n],Wv).
// Each wave owns 16 consecutive rows (8 KB). Every load instruction is
// lane i -> base + i*16B: contiguous 1KB, full 64B-line utilization
// (the old layout used 32B of every 64B line per instruction -> 2x
// VMEM line-requests -> 3.4 TB/s).
__global__ __launch_bounds__(BLOCK) void node_proj_kernel(
    const float* __restrict__ h,
    const float* __restrict__ W_w,   // [2*D]: first D = Wu, next D = Wv
    float*       __restrict__ pu,
    float*       __restrict__ pv,
    int n_nodes)
{
    const int lane = threadIdx.x & 63;
    const int wave = (blockIdx.x * BLOCK + threadIdx.x) >> 6;
    const int pos  = lane & 31;      // float4 index within a 512B row
    const int half = lane >> 5;      // which row of the chunk's pair

    // This lane always handles row floats [pos*4, pos*4+4).
    const float4 wu = reinterpret_cast<const float4*>(W_w)[pos];
    const float4 wv = reinterpret_cast<const float4*>(W_w)[32 + pos];

    const int nb = wave * ROWS_PER_WAVE;
    if (nb >= n_nodes) return;

    const float4* __restrict__ h4 = reinterpret_cast<const float4*>(h);

    if (nb + ROWS_PER_WAVE <= n_nodes) {
        // Fast path: issue all 8 perfectly-coalesced loads up front.
        const size_t base = (size_t)nb * 32 + lane;   // float4 units
        float4 x[CHUNKS];
#pragma unroll
        for (int c = 0; c < CHUNKS; ++c) x[c] = h4[base + (size_t)c * 64];

#pragma unroll
        for (int c = 0; c < CHUNKS; ++c) {
            float su = x[c].x * wu.x + x[c].y * wu.y + x[c].z * wu.z + x[c].w * wu.w;
            float sv = x[c].x * wv.x + x[c].y * wv.y + x[c].z * wv.z + x[c].w * wv.w;
#pragma unroll
            for (int off = 1; off < 32; off <<= 1) {   // stays within 32-lane half
                su += __shfl_xor(su, off, 64);
                sv += __shfl_xor(sv, off, 64);
            }
            if (pos == 0) {
                const int node = nb + c * 2 + half;
                pu[node] = su;
                pv[node] = sv;
            }
        }
    } else {
        // Tail wave (not taken for n_nodes=100000=6250*16): per-row guard.
        for (int c = 0; c < CHUNKS; ++c) {
            const int node = nb + c * 2 + half;
            if (node < n_nodes) {
                float4 x = h4[(size_t)node * 32 + pos];
                float su = x.x * wu.x + x.y * wu.y + x.z * wu.z + x.w * wu.w;
                float sv = x.x * wv.x + x.y * wv.y + x.z * wv.z + x.w * wv.w;
#pragma unroll
                for (int off = 1; off < 32; off <<= 1) {
                    su += __shfl_xor(su, off, 64);
                    sv += __shfl_xor(sv, off, 64);
                }
                if (pos == 0) { pu[node] = su; pv[node] = sv; }
            }
        }
    }
}

// Phase 2: out[e] = pu[src[e]] + pv[dst[e]] + b. 4 edges/thread. (R3 version;
// ~7us, bound by L3 service of random 64B-line gathers — separate problem.)
__global__ __launch_bounds__(BLOCK) void edge_score_kernel(
    const float* __restrict__ pu,
    const float* __restrict__ pv,
    const int*   __restrict__ src,
    const int*   __restrict__ dst,
    const float* __restrict__ W_b,
    float*       __restrict__ out,
    int n_edges)
{
    const float bias = W_b[0];
    const int n_quads = n_edges >> 2;
    const int q = blockIdx.x * BLOCK + threadIdx.x;

    if (q < n_quads) {
        int4 s = reinterpret_cast<const int4*>(src)[q];
        int4 d = reinterpret_cast<const int4*>(dst)[q];
        float4 r;
        r.x = pu[s.x] + pv[d.x] + bias;
        r.y = pu[s.y] + pv[d.y] + bias;
        r.z = pu[s.z] + pv[d.z] + bias;
        r.w = pu[s.w] + pv[d.w] + bias;
        reinterpret_cast<float4*>(out)[q] = r;
    }

    if (q == 0) {
        for (int e = n_quads << 2; e < n_edges; ++e)
            out[e] = pu[src[e]] + pv[dst[e]] + bias;
    }
}

extern "C" void kernel_launch(void* const* d_in, const int* in_sizes, int n_in,
                              void* d_out, int out_size, void* d_ws, size_t ws_size,
                              hipStream_t stream)
{
    const float* h   = (const float*)d_in[0];
    const int*   src = (const int*)d_in[1];
    const int*   dst = (const int*)d_in[2];
    const float* W_w = (const float*)d_in[3];
    const float* W_b = (const float*)d_in[4];
    float*       out = (float*)d_out;

    const int n_nodes = in_sizes[0] / D;   // 100000
    const int n_edges = in_sizes[1];       // 625000

    float* pu = (float*)d_ws;
    float* pv = pu + n_nodes;

    // Phase 1: one wave per 16 rows.
    const int waves1  = (n_nodes + ROWS_PER_WAVE - 1) / ROWS_PER_WAVE;  // 6250
    const int blocks1 = (waves1 * 64 + BLOCK - 1) / BLOCK;              // 1563
    node_proj_kernel<<<blocks1, BLOCK, 0, stream>>>(h, W_w, pu, pv, n_nodes);

    // Phase 2: 4 edges per thread.
    const int n_quads = n_edges >> 2;                                   // 156250
    const int blocks2 = (n_quads + BLOCK - 1) / BLOCK;                  // 611
    edge_score_kernel<<<blocks2, BLOCK, 0, stream>>>(pu, pv, src, dst, W_b, out, n_edges);
}

// Round 8
// 22.626 us; speedup vs baseline: 8.1376x; 1.1055x over previous
//
#include <hip/hip_runtime.h>
#include <hip/hip_bf16.h>

#define D 128
#define BLOCK 256
#define ROWS_PER_WAVE 16            // 8 KB of h per wave
#define CHUNKS (ROWS_PER_WAVE / 2)  // 1 KB (2 rows) per chunk

// 32-wide sum reduction: levels 1-4 on the VALU pipe via DPP (quad_perm
// xor1/xor2, half-mirror, mirror -- valid involutions for a sum), level 5
// (lane^16) via one ds_swizzle. DS ops per value: 1 (vs 5 for shfl_xor
// butterfly). R6 was DS-pipe-bound at 80 DS/8KB; this is 16 DS/8KB.
// NOTE: dpp ctrl must be a compile-time constant -> template parameter.
template <int CTRL>
__device__ __forceinline__ float dpp_add(float x) {
    int yi = __builtin_amdgcn_update_dpp(0, __float_as_int(x), CTRL, 0xF, 0xF, true);
    return x + __int_as_float(yi);
}

__device__ __forceinline__ float reduce32(float x) {
    x = dpp_add<0xB1>(x);    // quad_perm [1,0,3,2]  : xor 1
    x = dpp_add<0x4E>(x);    // quad_perm [2,3,0,1]  : xor 2
    x = dpp_add<0x141>(x);   // row_half_mirror      : pairs across 4-groups
    x = dpp_add<0x140>(x);   // row_mirror           : pairs across 8-groups
    int yi = __builtin_amdgcn_ds_swizzle(__float_as_int(x), 0x401F); // xor 16
    return x + __int_as_float(yi);
}

// Phase 1: pu[n]=dot(h[n],Wu), pv[n]=dot(h[n],Wv).
// Wave owns 16 consecutive rows (8 KB); every load is lane i -> base+i*16B
// (contiguous 1KB/instr, minimal line-requests). Row r of a chunk lives in
// 32-lane half (r&1); reduction is the DPP tree above.
__global__ __launch_bounds__(BLOCK) void node_proj_kernel(
    const float* __restrict__ h,
    const float* __restrict__ W_w,   // [2*D]: first D = Wu, next D = Wv
    float*       __restrict__ pu,
    float*       __restrict__ pv,
    int n_nodes)
{
    const int lane = threadIdx.x & 63;
    const int wave = (blockIdx.x * BLOCK + threadIdx.x) >> 6;
    const int pos  = lane & 31;      // float4 index within a 512B row
    const int half = lane >> 5;      // which row of the chunk's pair

    const float4 wu = reinterpret_cast<const float4*>(W_w)[pos];
    const float4 wv = reinterpret_cast<const float4*>(W_w)[32 + pos];

    const int nb = wave * ROWS_PER_WAVE;
    if (nb >= n_nodes) return;

    const float4* __restrict__ h4 = reinterpret_cast<const float4*>(h);

    // Exact fit for n_nodes=100000 (6250 waves); guard handles generality.
    if (nb + ROWS_PER_WAVE <= n_nodes) {
        const size_t base = (size_t)nb * 32 + lane;   // float4 units
        float4 x[CHUNKS];
#pragma unroll
        for (int c = 0; c < CHUNKS; ++c) x[c] = h4[base + (size_t)c * 64];

#pragma unroll
        for (int c = 0; c < CHUNKS; ++c) {
            float su = x[c].x * wu.x + x[c].y * wu.y + x[c].z * wu.z + x[c].w * wu.w;
            float sv = x[c].x * wv.x + x[c].y * wv.y + x[c].z * wv.z + x[c].w * wv.w;
            su = reduce32(su);
            sv = reduce32(sv);
            if (pos == 0) {
                const int node = nb + c * 2 + half;
                pu[node] = su;
                pv[node] = sv;
            }
        }
    } else {
        for (int c = 0; c < CHUNKS; ++c) {
            const int node = nb + c * 2 + half;
            if (node < n_nodes) {
                float4 x = h4[(size_t)node * 32 + pos];
                float su = x.x * wu.x + x.y * wu.y + x.z * wu.z + x.w * wu.w;
                float sv = x.x * wv.x + x.y * wv.y + x.z * wv.z + x.w * wv.w;
                su = reduce32(su);
                sv = reduce32(sv);
                if (pos == 0) { pu[node] = su; pv[node] = sv; }
            }
        }
    }
}

// Phase 2: out[e] = pu[src[e]] + pv[dst[e]] + b. 4 edges/thread. (unchanged)
__global__ __launch_bounds__(BLOCK) void edge_score_kernel(
    const float* __restrict__ pu,
    const float* __restrict__ pv,
    const int*   __restrict__ src,
    const int*   __restrict__ dst,
    const float* __restrict__ W_b,
    float*       __restrict__ out,
    int n_edges)
{
    const float bias = W_b[0];
    const int n_quads = n_edges >> 2;
    const int q = blockIdx.x * BLOCK + threadIdx.x;

    if (q < n_quads) {
        int4 s = reinterpret_cast<const int4*>(src)[q];
        int4 d = reinterpret_cast<const int4*>(dst)[q];
        float4 r;
        r.x = pu[s.x] + pv[d.x] + bias;
        r.y = pu[s.y] + pv[d.y] + bias;
        r.z = pu[s.z] + pv[d.z] + bias;
        r.w = pu[s.w] + pv[d.w] + bias;
        reinterpret_cast<float4*>(out)[q] = r;
    }

    if (q == 0) {
        for (int e = n_quads << 2; e < n_edges; ++e)
            out[e] = pu[src[e]] + pv[dst[e]] + bias;
    }
}

extern "C" void kernel_launch(void* const* d_in, const int* in_sizes, int n_in,
                              void* d_out, int out_size, void* d_ws, size_t ws_size,
                              hipStream_t stream)
{
    const float* h   = (const float*)d_in[0];
    const int*   src = (const int*)d_in[1];
    const int*   dst = (const int*)d_in[2];
    const float* W_w = (const float*)d_in[3];
    const float* W_b = (const float*)d_in[4];
    float*       out = (float*)d_out;

    const int n_nodes = in_sizes[0] / D;   // 100000
    const int n_edges = in_sizes[1];       // 625000

    float* pu = (float*)d_ws;
    float* pv = pu + n_nodes;

    const int waves1  = (n_nodes + ROWS_PER_WAVE - 1) / ROWS_PER_WAVE;  // 6250
    const int blocks1 = (waves1 * 64 + BLOCK - 1) / BLOCK;              // 1563
    node_proj_kernel<<<blocks1, BLOCK, 0, stream>>>(h, W_w, pu, pv, n_nodes);

    const int n_quads = n_edges >> 2;                                   // 156250
    const int blocks2 = (n_quads + BLOCK - 1) / BLOCK;                  // 611
    edge_score_kernel<<<blocks2, BLOCK, 0, stream>>>(pu, pv, src, dst, W_b, out, n_edges);
}